// Round 9
// baseline (207.443 us; speedup 1.0000x reference)
//
#include <hip/hip_runtime.h>
#include <hip/hip_bf16.h>

#define N_NODES 50000
#define N_EDGES 1600000
#define HEADS 8
#define HFD 16
#define CH 128      // channels

// bucketing: bucket = dst>>7 (128 dst nodes per bucket)
#define PART 128
#define NB 391              // ceil(50000/128)
#define BCAP 5120           // edge capacity per bucket (mean 4096, +16 sigma)
#define PA_T 512
#define PA_CHUNK 3200       // edges per pass-A block
#define PA_PER 7            // 512*7 = 3584 >= 3200
#define PA_BLOCKS 500       // 500*3200 = 1.6M
#define EMB_BLOCKS 391      // 391*8 waves = 3128 tiles >= 3125

// k_aggr geometry: one block per QUARTER bucket (32 dsts), 256 threads
#define QPART 32
#define QCAP 1536           // per-quarter edge capacity (mean 1024, +16 sigma)
#define AG_TASKS (NB * 4)   // 1564
#define AG_BLOCKS 1568      // 8 * 196, multiple of 8 for XCD swizzle

typedef __bf16 bf16x8 __attribute__((ext_vector_type(8)));
typedef __bf16 bf16x4 __attribute__((ext_vector_type(4)));
typedef float f32x4 __attribute__((ext_vector_type(4)));
typedef float f32x2 __attribute__((ext_vector_type(2)));

__device__ __forceinline__ float bf_lo(unsigned u) { return __uint_as_float(u << 16); }
__device__ __forceinline__ float bf_hi(unsigned u) { return __uint_as_float(u & 0xffff0000u); }

// ---------------------------------------------------------------------------
// Prep kernel: (a) split W f32 -> bf16 hi/lo; (b) build the 16x128 effective
// logit tile Veff; (c) zero bucket_cnt.
// ---------------------------------------------------------------------------
__global__ __launch_bounds__(256) void k_splitw(const float* __restrict__ W,
                                                const float* __restrict__ aL,
                                                const float* __restrict__ aR,
                                                __bf16* __restrict__ Whi,
                                                __bf16* __restrict__ Wlo,
                                                __bf16* __restrict__ Vhi,
                                                __bf16* __restrict__ Vlo,
                                                int* __restrict__ bucket_cnt) {
  int t = blockIdx.x * 256 + threadIdx.x;
  if (t < NB) bucket_cnt[t] = 0;
  if (t < CH * CH / 4) {
    f32x4 v = ((const f32x4*)W)[t];
    bf16x4 h, l;
#pragma unroll
    for (int i = 0; i < 4; ++i) {
      __bf16 hb = (__bf16)v[i];
      h[i] = hb;
      l[i] = (__bf16)(v[i] - (float)hb);
    }
    ((bf16x4*)Whi)[t] = h;
    ((bf16x4*)Wlo)[t] = l;
  }
  if (t < 16 * CH) {
    int j = t >> 7;          // 0..15: logit row (0..7 left, 8..15 right)
    int k = t & 127;         // input channel
    int h = j & 7;
    const float* a = (j < 8) ? aL : aR;
    float v = 0.f;
#pragma unroll
    for (int c = 0; c < HFD; ++c) v += W[(h * HFD + c) * CH + k] * a[c * HEADS + h];
    __bf16 hb = (__bf16)v;
    Vhi[t] = hb;
    Vlo[t] = (__bf16)(v - (float)hb);
  }
}

// ---------------------------------------------------------------------------
// FUSED pass-A + embedding (proven R6). Blocks 0..499: bucket edges by
// dst>>7. Blocks 500..890: emb via MFMA, one 16-node tile per wave.
// ---------------------------------------------------------------------------
__global__ __launch_bounds__(PA_T) void k_prep(const int* __restrict__ ei,
                                               int* __restrict__ bucket_cnt,
                                               unsigned* __restrict__ ebuf,
                                               const float* __restrict__ X,
                                               const __bf16* __restrict__ Whi,
                                               const __bf16* __restrict__ Wlo,
                                               const __bf16* __restrict__ Vhi,
                                               const __bf16* __restrict__ Vlo,
                                               __bf16* __restrict__ embb,
                                               float* __restrict__ leftp,
                                               float* __restrict__ rightp) {
  __shared__ unsigned sp[PA_CHUNK];   // 12.8 KB sorted edges
  __shared__ int hist[NB];
  __shared__ int lcur[NB];
  __shared__ int wbase[NB];
  __shared__ int wpart[8];
  int t = threadIdx.x;

  if (blockIdx.x >= PA_BLOCKS) {
    // ---------------- emb part: one 16-node tile per wave ----------------
    int ntile = (blockIdx.x - PA_BLOCKS) * 8 + (t >> 6);
    if (ntile >= N_NODES / 16) return;
    int lane = t & 63;
    int c = lane & 15, quad = lane >> 4;
    const float* xp = X + (size_t)(ntile * 16 + c) * CH + quad * 8;
    bf16x8 xh[4], xl[4];
#pragma unroll
    for (int ks = 0; ks < 4; ++ks) {
      float4 x0 = *(const float4*)(xp + ks * 32);
      float4 x1 = *(const float4*)(xp + ks * 32 + 4);
      float xv[8] = {x0.x, x0.y, x0.z, x0.w, x1.x, x1.y, x1.z, x1.w};
#pragma unroll
      for (int j = 0; j < 8; ++j) {
        __bf16 hb = (__bf16)xv[j];
        xh[ks][j] = hb;
        xl[ks][j] = (__bf16)(xv[j] - (float)hb);
      }
    }
#pragma unroll
    for (int h = 0; h < HEADS; ++h) {
      const __bf16* wp = Whi + (size_t)(h * 16 + c) * CH + quad * 8;
      const __bf16* wlp = Wlo + (size_t)(h * 16 + c) * CH + quad * 8;
      f32x4 acc = {0.f, 0.f, 0.f, 0.f};
#pragma unroll
      for (int ks = 0; ks < 4; ++ks) {
        bf16x8 wh = *(const bf16x8*)(wp + ks * 32);
        bf16x8 wl = *(const bf16x8*)(wlp + ks * 32);
        acc = __builtin_amdgcn_mfma_f32_16x16x32_bf16(xl[ks], wh, acc, 0, 0, 0);
        acc = __builtin_amdgcn_mfma_f32_16x16x32_bf16(xh[ks], wl, acc, 0, 0, 0);
        acc = __builtin_amdgcn_mfma_f32_16x16x32_bf16(xh[ks], wh, acc, 0, 0, 0);
      }
#pragma unroll
      for (int r = 0; r < 4; ++r) {
        int node = ntile * 16 + quad * 4 + r;
        embb[(size_t)node * CH + h * HFD + c] = (__bf16)acc[r];
      }
    }
    // logit tile: j<8 -> left head j, j>=8 -> right head j-8
    {
      const __bf16* vp = Vhi + (size_t)c * CH + quad * 8;
      const __bf16* vlp = Vlo + (size_t)c * CH + quad * 8;
      f32x4 acc = {0.f, 0.f, 0.f, 0.f};
#pragma unroll
      for (int ks = 0; ks < 4; ++ks) {
        bf16x8 vh = *(const bf16x8*)(vp + ks * 32);
        bf16x8 vl = *(const bf16x8*)(vlp + ks * 32);
        acc = __builtin_amdgcn_mfma_f32_16x16x32_bf16(xl[ks], vh, acc, 0, 0, 0);
        acc = __builtin_amdgcn_mfma_f32_16x16x32_bf16(xh[ks], vl, acc, 0, 0, 0);
        acc = __builtin_amdgcn_mfma_f32_16x16x32_bf16(xh[ks], vh, acc, 0, 0, 0);
      }
#pragma unroll
      for (int r = 0; r < 4; ++r) {
        int node = ntile * 16 + quad * 4 + r;
        if (c < 8) leftp[node * HEADS + c] = acc[r];
        else rightp[node * HEADS + (c - 8)] = acc[r];
      }
    }
    return;
  }

  // ---------------- bucket part (identical to proven R5/R6) ---------------
  int base = blockIdx.x * PA_CHUNK;
  for (int i = t; i < NB; i += PA_T) hist[i] = 0;
  __syncthreads();
  unsigned pk[PA_PER];
#pragma unroll
  for (int i = 0; i < PA_PER; ++i) {
    int e = t + i * PA_T;
    pk[i] = 0xffffffffu;
    if (e < PA_CHUNK) {
      int src = ei[base + e];
      int dst = ei[N_EDGES + base + e];
      pk[i] = ((unsigned)(dst >> 7) << 23) | ((unsigned)(dst & 127) << 16) |
              (unsigned)src;
      atomicAdd(&hist[dst >> 7], 1);
    }
  }
  __syncthreads();
  // inclusive scan over 512 (one bucket per thread): wave shfl scan + partials
  int hv = (t < NB) ? hist[t] : 0;
  int lane = t & 63, wid = t >> 6;
  int v = hv;
#pragma unroll
  for (int d = 1; d < 64; d <<= 1) {
    int o = __shfl_up(v, d);
    if (lane >= d) v += o;
  }
  if (lane == 63) wpart[wid] = v;
  __syncthreads();
  if (t < 8) {
    int pv = wpart[t];
#pragma unroll
    for (int d = 1; d < 8; d <<= 1) {
      int o = __shfl_up(pv, d);
      if (t >= d) pv += o;
    }
    wpart[t] = pv;
  }
  __syncthreads();
  int val = v + ((wid > 0) ? wpart[wid - 1] : 0);
  if (t < NB) {
    int lstart = val - hv;
    lcur[t] = lstart;
    int prior = hv ? atomicAdd(&bucket_cnt[t], hv) : 0;
    wbase[t] = t * BCAP + prior - lstart;
  }
  __syncthreads();
#pragma unroll
  for (int i = 0; i < PA_PER; ++i) {
    if (pk[i] != 0xffffffffu) {
      int b = pk[i] >> 23;
      int pos = atomicAdd(&lcur[b], 1);
      sp[pos] = pk[i];
    }
  }
  __syncthreads();
  for (int i = t; i < PA_CHUNK; i += PA_T) {
    unsigned p = sp[i];
    int b = p >> 23;
    int slot = wbase[b] + i;
    if (slot < (b + 1) * BCAP) ebuf[slot] = p;  // capacity guard (never fires)
  }
}

// ---------------------------------------------------------------------------
// Pull-aggregate v9: R1-proven prologue (quarter-bucket, 256 threads, 32-bin
// sort) + QUAD-BATCHED gather loop. Diagnosis R8: latency-bound, MLP ~6
// loads/wave-iter, avg miss latency ~700cyc -> VALUBusy 51%. Fix: 16 edges
// per iteration, all 12 loads (4 su + 4 uint4 + 4 leftp) issued
// unconditionally (index-clamped) in ONE basic block before a
// sched_barrier(0) fence and the consume cluster -> 2x loads in flight.
// __launch_bounds__(256,4) raises the VGPR budget to 128 so the allocator
// doesn't sink loads to their consumes (the R5/R6 collapse mechanism).
// Phasing dropped: FETCH 148 vs 200 MB was time-neutral (R8==R1) and its
// small bins cost ~20% masked-slot waste.
// ---------------------------------------------------------------------------
__global__ __launch_bounds__(256, 4) void k_aggr(const int* __restrict__ bucket_cnt,
                                                 const unsigned* __restrict__ ebuf,
                                                 const __bf16* __restrict__ embb,
                                                 const float* __restrict__ leftp,
                                                 const float* __restrict__ rightp,
                                                 const float* __restrict__ bias,
                                                 float* __restrict__ out) {
  __shared__ unsigned short su[QCAP];  // 3 KB: dstloc-sorted src ids (this quarter)
  __shared__ int hist[QPART];
  __shared__ int pfx[QPART];
  __shared__ int cur[QPART];
  // XCD-clustered task mapping: tasks T, T+1.. on the same XCD (xcd = bid%8)
  int T = (blockIdx.x & 7) * (AG_BLOCKS / 8) + (blockIdx.x >> 3);
  if (T >= AG_TASKS) return;
  int b = T >> 2;           // bucket
  int q = T & 3;            // quarter within bucket (dstloc 32q..32q+31)
  int t = threadIdx.x;
  int cnt = bucket_cnt[b];
  if (cnt > BCAP) cnt = BCAP;
  int ebase = b * BCAP;
  if (t < QPART) hist[t] = 0;
  __syncthreads();
  // pass 1: histogram this quarter's dstlocs (uint4 reads; tail over-read
  // stays inside the ebuf bucket window -> safe)
  for (int e4 = t * 4; e4 < cnt; e4 += 1024) {
    uint4 pp = *(const uint4*)(ebuf + ebase + e4);
    unsigned pj[4] = {pp.x, pp.y, pp.z, pp.w};
#pragma unroll
    for (int j = 0; j < 4; ++j) {
      if (e4 + j < cnt) {
        int dl = (pj[j] >> 16) & 127;
        if ((dl >> 5) == q) atomicAdd(&hist[dl & 31], 1);
      }
    }
  }
  __syncthreads();
  // 32-entry exclusive scan via wave-0 shuffles
  if (t < 64) {
    int v = (t < QPART) ? hist[t] : 0;
#pragma unroll
    for (int d = 1; d < QPART; d <<= 1) {
      int o = __shfl_up(v, d);
      if (t >= d) v += o;
    }
    if (t < QPART) {
      int ex = v - hist[t];
      pfx[t] = ex;
      cur[t] = ex;
    }
  }
  __syncthreads();
  // pass 2: scatter this quarter's srcs into su, sorted by dstloc
  for (int e4 = t * 4; e4 < cnt; e4 += 1024) {
    uint4 pp = *(const uint4*)(ebuf + ebase + e4);
    unsigned pj[4] = {pp.x, pp.y, pp.z, pp.w};
#pragma unroll
    for (int j = 0; j < 4; ++j) {
      if (e4 + j < cnt) {
        unsigned p = pj[j];
        int dl = (p >> 16) & 127;
        if ((dl >> 5) == q) {
          int pos = atomicAdd(&cur[dl & 31], 1);
          if (pos < QCAP) su[pos] = (unsigned short)(p & 0xffffu);
        }
      }
    }
  }
  __syncthreads();

  int wv = t >> 6;          // wave 0..3, each owns 8 dsts
  int lane = t & 63;
  int g = lane >> 4;        // edge slot 0..3
  int m = lane & 15;        // 16 B slice: channels 8m..8m+7
  int h = m >> 1;           // head of this slice
#pragma unroll 1
  for (int k = 0; k < 8; ++k) {
    int dl = wv * 8 + k;    // 0..31 within quarter
    int dst = b * PART + q * QPART + dl;
    bool valid = dst < N_NODES;
    int beg = pfx[dl];
    int cd = hist[dl];
    if (beg + cd > QCAP) cd = QCAP - beg;  // paranoia (never fires)
    float r = valid ? rightp[dst * HEADS + h] : 0.f;
    f32x2 acc0 = {0.f, 0.f}, acc1 = {0.f, 0.f};
    f32x2 acc2 = {0.f, 0.f}, acc3 = {0.f, 0.f};
    float dsum = 0.f;
    // quad-batched main loop: 16 edges/iter, 12 loads in flight, single BB
#pragma unroll 1
    for (int e0 = 0; e0 < cd; e0 += 16) {
      int i0 = e0 + g, i1 = e0 + 4 + g, i2 = e0 + 8 + g, i3 = e0 + 12 + g;
      bool a0 = i0 < cd, a1 = i1 < cd, a2 = i2 < cd, a3 = i3 < cd;
      int s0 = su[beg + (a0 ? i0 : 0)];
      int s1 = su[beg + (a1 ? i1 : 0)];
      int s2 = su[beg + (a2 ? i2 : 0)];
      int s3 = su[beg + (a3 ? i3 : 0)];
      uint4 u0 = ((const uint4*)(embb + (size_t)s0 * CH))[m];
      uint4 u1 = ((const uint4*)(embb + (size_t)s1 * CH))[m];
      uint4 u2 = ((const uint4*)(embb + (size_t)s2 * CH))[m];
      uint4 u3 = ((const uint4*)(embb + (size_t)s3 * CH))[m];
      float l0 = leftp[s0 * HEADS + h];
      float l1 = leftp[s1 * HEADS + h];
      float l2 = leftp[s2 * HEADS + h];
      float l3 = leftp[s3 * HEADS + h];
      __builtin_amdgcn_sched_barrier(0);
      float x0 = l0 + r; x0 = (x0 >= 0.f) ? x0 : 0.2f * x0;
      float w0 = a0 ? __expf(x0) : 0.f;
      float x1 = l1 + r; x1 = (x1 >= 0.f) ? x1 : 0.2f * x1;
      float w1 = a1 ? __expf(x1) : 0.f;
      float x2 = l2 + r; x2 = (x2 >= 0.f) ? x2 : 0.2f * x2;
      float w2 = a2 ? __expf(x2) : 0.f;
      float x3 = l3 + r; x3 = (x3 >= 0.f) ? x3 : 0.2f * x3;
      float w3 = a3 ? __expf(x3) : 0.f;
      dsum += (w0 + w1) + (w2 + w3);
      f32x2 wv0 = {w0, w0}, wv1 = {w1, w1}, wv2 = {w2, w2}, wv3 = {w3, w3};
      acc0 += wv0 * (f32x2){bf_lo(u0.x), bf_hi(u0.x)}
            + wv1 * (f32x2){bf_lo(u1.x), bf_hi(u1.x)}
            + wv2 * (f32x2){bf_lo(u2.x), bf_hi(u2.x)}
            + wv3 * (f32x2){bf_lo(u3.x), bf_hi(u3.x)};
      acc1 += wv0 * (f32x2){bf_lo(u0.y), bf_hi(u0.y)}
            + wv1 * (f32x2){bf_lo(u1.y), bf_hi(u1.y)}
            + wv2 * (f32x2){bf_lo(u2.y), bf_hi(u2.y)}
            + wv3 * (f32x2){bf_lo(u3.y), bf_hi(u3.y)};
      acc2 += wv0 * (f32x2){bf_lo(u0.z), bf_hi(u0.z)}
            + wv1 * (f32x2){bf_lo(u1.z), bf_hi(u1.z)}
            + wv2 * (f32x2){bf_lo(u2.z), bf_hi(u2.z)}
            + wv3 * (f32x2){bf_lo(u3.z), bf_hi(u3.z)};
      acc3 += wv0 * (f32x2){bf_lo(u0.w), bf_hi(u0.w)}
            + wv1 * (f32x2){bf_lo(u1.w), bf_hi(u1.w)}
            + wv2 * (f32x2){bf_lo(u2.w), bf_hi(u2.w)}
            + wv3 * (f32x2){bf_lo(u3.w), bf_hi(u3.w)};
    }
    // reduce over the 4 edge slots (lane bits 4,5)
    float a0 = acc0.x, a1 = acc0.y, a2 = acc1.x, a3 = acc1.y;
    float a4 = acc2.x, a5 = acc2.y, a6 = acc3.x, a7 = acc3.y;
#pragma unroll
    for (int mask = 16; mask <= 32; mask <<= 1) {
      dsum += __shfl_xor(dsum, mask);
      a0 += __shfl_xor(a0, mask);
      a1 += __shfl_xor(a1, mask);
      a2 += __shfl_xor(a2, mask);
      a3 += __shfl_xor(a3, mask);
      a4 += __shfl_xor(a4, mask);
      a5 += __shfl_xor(a5, mask);
      a6 += __shfl_xor(a6, mask);
      a7 += __shfl_xor(a7, mask);
    }
    if (g == 0 && valid) {
      float inv = (dsum > 0.f) ? 1.0f / dsum : 0.f;
      float4 b0 = ((const float4*)bias)[2 * m];
      float4 b1 = ((const float4*)bias)[2 * m + 1];
      float4 o0 = {a0 * inv + b0.x, a1 * inv + b0.y,
                   a2 * inv + b0.z, a3 * inv + b0.w};
      float4 o1 = {a4 * inv + b1.x, a5 * inv + b1.y,
                   a6 * inv + b1.z, a7 * inv + b1.w};
      ((float4*)(out + (size_t)dst * CH))[2 * m] = o0;
      ((float4*)(out + (size_t)dst * CH))[2 * m + 1] = o1;
    }
  }
}

extern "C" void kernel_launch(void* const* d_in, const int* in_sizes, int n_in,
                              void* d_out, int out_size, void* d_ws, size_t ws_size,
                              hipStream_t stream) {
  const float* X = (const float*)d_in[0];
  const int* ei = (const int*)d_in[1];
  const float* W = (const float*)d_in[2];
  const float* al = (const float*)d_in[3];
  const float* ar = (const float*)d_in[4];
  const float* bias = (const float*)d_in[5];
  float* out = (float*)d_out;

  // workspace layout (~22.6 MB); all segments 16 B-aligned
  unsigned* ebuf = (unsigned*)d_ws;                       // NB*BCAP u32 (8.0 MB)
  __bf16* embb = (__bf16*)(ebuf + (size_t)NB * BCAP);     // N*128 bf16 (12.8 MB)
  __bf16* Whi = embb + (size_t)N_NODES * CH;              // 16K bf16
  __bf16* Wlo = Whi + CH * CH;                            // 16K bf16
  __bf16* Vhi = Wlo + CH * CH;                            // 2K bf16
  __bf16* Vlo = Vhi + 16 * CH;                            // 2K bf16
  float* leftp = (float*)(Vlo + 16 * CH);                 // N*8 f32
  float* rightp = leftp + (size_t)N_NODES * HEADS;        // N*8 f32
  int* bucket_cnt = (int*)(rightp + (size_t)N_NODES * HEADS);  // NB int

  k_splitw<<<16, 256, 0, stream>>>(W, al, ar, Whi, Wlo, Vhi, Vlo, bucket_cnt);
  k_prep<<<PA_BLOCKS + EMB_BLOCKS, PA_T, 0, stream>>>(ei, bucket_cnt, ebuf, X,
                                                      Whi, Wlo, Vhi, Vlo, embb,
                                                      leftp, rightp);
  k_aggr<<<AG_BLOCKS, 256, 0, stream>>>(bucket_cnt, ebuf, embb, leftp, rightp, bias, out);
}

// Round 10
// 203.042 us; speedup vs baseline: 1.0217x; 1.0217x over previous
//
#include <hip/hip_runtime.h>
#include <hip/hip_bf16.h>

#define N_NODES 50000
#define N_EDGES 1600000
#define HEADS 8
#define HFD 16
#define CH 128      // channels

// bucketing: bucket = dst>>7 (128 dst nodes per bucket)
#define PART 128
#define NB 391              // ceil(50000/128)
#define BCAP 5120           // edge capacity per bucket (mean 4096, +16 sigma)
#define PA_T 512
#define PA_CHUNK 6400       // edges per pass-A block (doubled: 16-edge runs ->
                            // 64B sector-aligned ebuf writes, half the scans)
#define PA_PER 13           // 512*13 = 6656 >= 6400
#define PA_BLOCKS 250       // 250*6400 = 1.6M
#define EMB_BLOCKS 391      // 391*8 waves = 3128 tiles >= 3125

// k_aggr geometry: one block per QUARTER bucket (32 dsts), 256 threads
#define QPART 32
#define QCAP 1536           // per-quarter edge capacity (mean 1024, +16 sigma)
#define AG_TASKS (NB * 4)   // 1564
#define AG_BLOCKS 1568      // 8 * 196, multiple of 8 for XCD swizzle

typedef __bf16 bf16x8 __attribute__((ext_vector_type(8)));
typedef __bf16 bf16x4 __attribute__((ext_vector_type(4)));
typedef float f32x4 __attribute__((ext_vector_type(4)));
typedef float f32x2 __attribute__((ext_vector_type(2)));

__device__ __forceinline__ float bf_lo(unsigned u) { return __uint_as_float(u << 16); }
__device__ __forceinline__ float bf_hi(unsigned u) { return __uint_as_float(u & 0xffff0000u); }

// ---------------------------------------------------------------------------
// Prep kernel: (a) split W f32 -> bf16 hi/lo; (b) build the 16x128 effective
// logit tile Veff; (c) zero bucket_cnt.
// ---------------------------------------------------------------------------
__global__ __launch_bounds__(256) void k_splitw(const float* __restrict__ W,
                                                const float* __restrict__ aL,
                                                const float* __restrict__ aR,
                                                __bf16* __restrict__ Whi,
                                                __bf16* __restrict__ Wlo,
                                                __bf16* __restrict__ Vhi,
                                                __bf16* __restrict__ Vlo,
                                                int* __restrict__ bucket_cnt) {
  int t = blockIdx.x * 256 + threadIdx.x;
  if (t < NB) bucket_cnt[t] = 0;
  if (t < CH * CH / 4) {
    f32x4 v = ((const f32x4*)W)[t];
    bf16x4 h, l;
#pragma unroll
    for (int i = 0; i < 4; ++i) {
      __bf16 hb = (__bf16)v[i];
      h[i] = hb;
      l[i] = (__bf16)(v[i] - (float)hb);
    }
    ((bf16x4*)Whi)[t] = h;
    ((bf16x4*)Wlo)[t] = l;
  }
  if (t < 16 * CH) {
    int j = t >> 7;          // 0..15: logit row (0..7 left, 8..15 right)
    int k = t & 127;         // input channel
    int h = j & 7;
    const float* a = (j < 8) ? aL : aR;
    float v = 0.f;
#pragma unroll
    for (int c = 0; c < HFD; ++c) v += W[(h * HFD + c) * CH + k] * a[c * HEADS + h];
    __bf16 hb = (__bf16)v;
    Vhi[t] = hb;
    Vlo[t] = (__bf16)(v - (float)hb);
  }
}

// ---------------------------------------------------------------------------
// FUSED pass-A + embedding. Blocks 0..249: bucket 6400 edges each by dst>>7
// (runs of ~16 edges per (block,bucket) -> 64B-aligned ebuf writes).
// Blocks 250..640: emb via MFMA, one 16-node tile per wave.
// ---------------------------------------------------------------------------
__global__ __launch_bounds__(PA_T) void k_prep(const int* __restrict__ ei,
                                               int* __restrict__ bucket_cnt,
                                               unsigned* __restrict__ ebuf,
                                               const float* __restrict__ X,
                                               const __bf16* __restrict__ Whi,
                                               const __bf16* __restrict__ Wlo,
                                               const __bf16* __restrict__ Vhi,
                                               const __bf16* __restrict__ Vlo,
                                               __bf16* __restrict__ embb,
                                               float* __restrict__ leftp,
                                               float* __restrict__ rightp) {
  __shared__ unsigned sp[PA_CHUNK];   // 25.6 KB sorted edges
  __shared__ int hist[NB];
  __shared__ int lcur[NB];
  __shared__ int wbase[NB];
  __shared__ int wpart[8];
  int t = threadIdx.x;

  if (blockIdx.x >= PA_BLOCKS) {
    // ---------------- emb part: one 16-node tile per wave ----------------
    int ntile = (blockIdx.x - PA_BLOCKS) * 8 + (t >> 6);
    if (ntile >= N_NODES / 16) return;
    int lane = t & 63;
    int c = lane & 15, quad = lane >> 4;
    const float* xp = X + (size_t)(ntile * 16 + c) * CH + quad * 8;
    bf16x8 xh[4], xl[4];
#pragma unroll
    for (int ks = 0; ks < 4; ++ks) {
      float4 x0 = *(const float4*)(xp + ks * 32);
      float4 x1 = *(const float4*)(xp + ks * 32 + 4);
      float xv[8] = {x0.x, x0.y, x0.z, x0.w, x1.x, x1.y, x1.z, x1.w};
#pragma unroll
      for (int j = 0; j < 8; ++j) {
        __bf16 hb = (__bf16)xv[j];
        xh[ks][j] = hb;
        xl[ks][j] = (__bf16)(xv[j] - (float)hb);
      }
    }
#pragma unroll
    for (int h = 0; h < HEADS; ++h) {
      const __bf16* wp = Whi + (size_t)(h * 16 + c) * CH + quad * 8;
      const __bf16* wlp = Wlo + (size_t)(h * 16 + c) * CH + quad * 8;
      f32x4 acc = {0.f, 0.f, 0.f, 0.f};
#pragma unroll
      for (int ks = 0; ks < 4; ++ks) {
        bf16x8 wh = *(const bf16x8*)(wp + ks * 32);
        bf16x8 wl = *(const bf16x8*)(wlp + ks * 32);
        acc = __builtin_amdgcn_mfma_f32_16x16x32_bf16(xl[ks], wh, acc, 0, 0, 0);
        acc = __builtin_amdgcn_mfma_f32_16x16x32_bf16(xh[ks], wl, acc, 0, 0, 0);
        acc = __builtin_amdgcn_mfma_f32_16x16x32_bf16(xh[ks], wh, acc, 0, 0, 0);
      }
#pragma unroll
      for (int r = 0; r < 4; ++r) {
        int node = ntile * 16 + quad * 4 + r;
        embb[(size_t)node * CH + h * HFD + c] = (__bf16)acc[r];
      }
    }
    // logit tile: j<8 -> left head j, j>=8 -> right head j-8
    {
      const __bf16* vp = Vhi + (size_t)c * CH + quad * 8;
      const __bf16* vlp = Vlo + (size_t)c * CH + quad * 8;
      f32x4 acc = {0.f, 0.f, 0.f, 0.f};
#pragma unroll
      for (int ks = 0; ks < 4; ++ks) {
        bf16x8 vh = *(const bf16x8*)(vp + ks * 32);
        bf16x8 vl = *(const bf16x8*)(vlp + ks * 32);
        acc = __builtin_amdgcn_mfma_f32_16x16x32_bf16(xl[ks], vh, acc, 0, 0, 0);
        acc = __builtin_amdgcn_mfma_f32_16x16x32_bf16(xh[ks], vl, acc, 0, 0, 0);
        acc = __builtin_amdgcn_mfma_f32_16x16x32_bf16(xh[ks], vh, acc, 0, 0, 0);
      }
#pragma unroll
      for (int r = 0; r < 4; ++r) {
        int node = ntile * 16 + quad * 4 + r;
        if (c < 8) leftp[node * HEADS + c] = acc[r];
        else rightp[node * HEADS + (c - 8)] = acc[r];
      }
    }
    return;
  }

  // ---------------- bucket part (R5 algorithm, 6400-edge chunks) ----------
  int base = blockIdx.x * PA_CHUNK;
  for (int i = t; i < NB; i += PA_T) hist[i] = 0;
  __syncthreads();
  unsigned pk[PA_PER];
#pragma unroll
  for (int i = 0; i < PA_PER; ++i) {
    int e = t + i * PA_T;
    pk[i] = 0xffffffffu;
    if (e < PA_CHUNK) {
      int src = ei[base + e];
      int dst = ei[N_EDGES + base + e];
      pk[i] = ((unsigned)(dst >> 7) << 23) | ((unsigned)(dst & 127) << 16) |
              (unsigned)src;
      atomicAdd(&hist[dst >> 7], 1);
    }
  }
  __syncthreads();
  // inclusive scan over 512 (one bucket per thread): wave shfl scan + partials
  int hv = (t < NB) ? hist[t] : 0;
  int lane = t & 63, wid = t >> 6;
  int v = hv;
#pragma unroll
  for (int d = 1; d < 64; d <<= 1) {
    int o = __shfl_up(v, d);
    if (lane >= d) v += o;
  }
  if (lane == 63) wpart[wid] = v;
  __syncthreads();
  if (t < 8) {
    int pv = wpart[t];
#pragma unroll
    for (int d = 1; d < 8; d <<= 1) {
      int o = __shfl_up(pv, d);
      if (t >= d) pv += o;
    }
    wpart[t] = pv;
  }
  __syncthreads();
  int val = v + ((wid > 0) ? wpart[wid - 1] : 0);
  if (t < NB) {
    int lstart = val - hv;
    lcur[t] = lstart;
    int prior = hv ? atomicAdd(&bucket_cnt[t], hv) : 0;
    wbase[t] = t * BCAP + prior - lstart;
  }
  __syncthreads();
#pragma unroll
  for (int i = 0; i < PA_PER; ++i) {
    if (pk[i] != 0xffffffffu) {
      int b = pk[i] >> 23;
      int pos = atomicAdd(&lcur[b], 1);
      sp[pos] = pk[i];
    }
  }
  __syncthreads();
  for (int i = t; i < PA_CHUNK; i += PA_T) {
    unsigned p = sp[i];
    int b = p >> 23;
    int slot = wbase[b] + i;
    if (slot < (b + 1) * BCAP) ebuf[slot] = p;  // capacity guard (never fires)
  }
}

// ---------------------------------------------------------------------------
// Fused CSR-sort + pull-aggregate: the proven R5 body (quarter-bucket, 256
// threads, uniform per-wave dst loop, f32x2 packed acc, depth-3 declared /
// depth-collapsed by regalloc -- measured best 73.9us), sched_barriers
// removed (R6 proved them no-ops). R8/R9 established this kernel sits at a
// random-gather service ceiling (~5.6 TB/s of 64B sectors): invariant to
// pipeline depth, wave supply, and FETCH 109-200MB. Left as-is.
// ---------------------------------------------------------------------------
__global__ __launch_bounds__(256) void k_aggr(const int* __restrict__ bucket_cnt,
                                              const unsigned* __restrict__ ebuf,
                                              const __bf16* __restrict__ embb,
                                              const float* __restrict__ leftp,
                                              const float* __restrict__ rightp,
                                              const float* __restrict__ bias,
                                              float* __restrict__ out) {
  __shared__ unsigned short su[QCAP];  // 3 KB: dstloc-sorted src ids (this quarter)
  __shared__ int hist[QPART];
  __shared__ int pfx[QPART];
  __shared__ int cur[QPART];
  // XCD-clustered task mapping: tasks T, T+1.. on the same XCD (xcd = bid%8)
  int T = (blockIdx.x & 7) * (AG_BLOCKS / 8) + (blockIdx.x >> 3);
  if (T >= AG_TASKS) return;
  int b = T >> 2;           // bucket
  int q = T & 3;            // quarter within bucket (dstloc 32q..32q+31)
  int t = threadIdx.x;
  int cnt = bucket_cnt[b];
  if (cnt > BCAP) cnt = BCAP;
  int ebase = b * BCAP;
  if (t < QPART) hist[t] = 0;
  __syncthreads();
  // pass 1: histogram this quarter's dstlocs (uint4 reads; tail over-read
  // stays inside the ebuf bucket window -> safe)
  for (int e4 = t * 4; e4 < cnt; e4 += 1024) {
    uint4 pp = *(const uint4*)(ebuf + ebase + e4);
    unsigned pj[4] = {pp.x, pp.y, pp.z, pp.w};
#pragma unroll
    for (int j = 0; j < 4; ++j) {
      if (e4 + j < cnt) {
        int dl = (pj[j] >> 16) & 127;
        if ((dl >> 5) == q) atomicAdd(&hist[dl & 31], 1);
      }
    }
  }
  __syncthreads();
  // 32-entry exclusive scan via wave-0 shuffles
  if (t < 64) {
    int v = (t < QPART) ? hist[t] : 0;
#pragma unroll
    for (int d = 1; d < QPART; d <<= 1) {
      int o = __shfl_up(v, d);
      if (t >= d) v += o;
    }
    if (t < QPART) {
      int ex = v - hist[t];
      pfx[t] = ex;
      cur[t] = ex;
    }
  }
  __syncthreads();
  // pass 2: scatter this quarter's srcs into su, sorted by dstloc
  for (int e4 = t * 4; e4 < cnt; e4 += 1024) {
    uint4 pp = *(const uint4*)(ebuf + ebase + e4);
    unsigned pj[4] = {pp.x, pp.y, pp.z, pp.w};
#pragma unroll
    for (int j = 0; j < 4; ++j) {
      if (e4 + j < cnt) {
        unsigned p = pj[j];
        int dl = (p >> 16) & 127;
        if ((dl >> 5) == q) {
          int pos = atomicAdd(&cur[dl & 31], 1);
          if (pos < QCAP) su[pos] = (unsigned short)(p & 0xffffu);
        }
      }
    }
  }
  __syncthreads();

  int wv = t >> 6;          // wave 0..3, each owns 8 dsts
  int lane = t & 63;
  int g = lane >> 4;        // edge group 0..3
  int m = lane & 15;        // 16 B slice: channels 8m..8m+7
  int h = m >> 1;           // head of this slice
#pragma unroll 1
  for (int k = 0; k < 8; ++k) {
    int dl = wv * 8 + k;    // 0..31 within quarter
    int dst = b * PART + q * QPART + dl;
    bool valid = dst < N_NODES;
    int beg = pfx[dl];
    int cd = hist[dl];
    if (beg + cd > QCAP) cd = QCAP - beg;  // paranoia (never fires)
    float r = valid ? rightp[dst * HEADS + h] : 0.f;
    f32x2 acc2[4];
    acc2[0] = (f32x2){0.f, 0.f};
    acc2[1] = (f32x2){0.f, 0.f};
    acc2[2] = (f32x2){0.f, 0.f};
    acc2[3] = (f32x2){0.f, 0.f};
    float dsum = 0.f;
    if (cd > 0) {
      int sA0, sA1, sB0, sB1, sC0, sC1;
      uint4 uA0, uA1, uB0, uB1, uC0, uC1;
      float lA0, lA1, lB0, lB1, lC0, lC1;
#define STAGE(E0, s0, s1, u0, u1, l0, l1)                          \
      {                                                            \
        int i0 = (E0) + g, i1 = (E0) + 4 + g;                      \
        s0 = su[beg + ((i0 < cd) ? i0 : 0)];                       \
        s1 = su[beg + ((i1 < cd) ? i1 : 0)];                       \
        u0 = ((const uint4*)(embb + (size_t)s0 * CH))[m];          \
        u1 = ((const uint4*)(embb + (size_t)s1 * CH))[m];          \
        l0 = leftp[s0 * HEADS + h];                                \
        l1 = leftp[s1 * HEADS + h];                                \
      }
#define CONSUME(E0, u0, u1, l0, l1)                                \
      {                                                            \
        bool a0 = (E0) + g < cd, a1 = (E0) + 4 + g < cd;           \
        float x0 = l0 + r;                                         \
        x0 = (x0 >= 0.f) ? x0 : 0.2f * x0;                         \
        float w0 = a0 ? __expf(x0) : 0.f;                          \
        float x1 = l1 + r;                                         \
        x1 = (x1 >= 0.f) ? x1 : 0.2f * x1;                         \
        float w1 = a1 ? __expf(x1) : 0.f;                          \
        dsum += w0 + w1;                                           \
        f32x2 wv0 = {w0, w0}, wv1 = {w1, w1};                      \
        acc2[0] += wv0 * (f32x2){bf_lo(u0.x), bf_hi(u0.x)}         \
                 + wv1 * (f32x2){bf_lo(u1.x), bf_hi(u1.x)};        \
        acc2[1] += wv0 * (f32x2){bf_lo(u0.y), bf_hi(u0.y)}         \
                 + wv1 * (f32x2){bf_lo(u1.y), bf_hi(u1.y)};        \
        acc2[2] += wv0 * (f32x2){bf_lo(u0.z), bf_hi(u0.z)}         \
                 + wv1 * (f32x2){bf_lo(u1.z), bf_hi(u1.z)};        \
        acc2[3] += wv0 * (f32x2){bf_lo(u0.w), bf_hi(u0.w)}         \
                 + wv1 * (f32x2){bf_lo(u1.w), bf_hi(u1.w)};        \
      }
      STAGE(0, sA0, sA1, uA0, uA1, lA0, lA1);
      if (8 < cd) STAGE(8, sB0, sB1, uB0, uB1, lB0, lB1);
      int e0 = 0;
      while (true) {
        if (e0 + 16 < cd) STAGE(e0 + 16, sC0, sC1, uC0, uC1, lC0, lC1);
        CONSUME(e0, uA0, uA1, lA0, lA1);
        e0 += 8;
        if (e0 >= cd) break;
        if (e0 + 16 < cd) STAGE(e0 + 16, sA0, sA1, uA0, uA1, lA0, lA1);
        CONSUME(e0, uB0, uB1, lB0, lB1);
        e0 += 8;
        if (e0 >= cd) break;
        if (e0 + 16 < cd) STAGE(e0 + 16, sB0, sB1, uB0, uB1, lB0, lB1);
        CONSUME(e0, uC0, uC1, lC0, lC1);
        e0 += 8;
        if (e0 >= cd) break;
      }
#undef STAGE
#undef CONSUME
    }
    // reduce over the 4 edge groups (lane bits 4,5)
    float a0 = acc2[0].x, a1 = acc2[0].y, a2 = acc2[1].x, a3 = acc2[1].y;
    float a4 = acc2[2].x, a5 = acc2[2].y, a6 = acc2[3].x, a7 = acc2[3].y;
#pragma unroll
    for (int mask = 16; mask <= 32; mask <<= 1) {
      dsum += __shfl_xor(dsum, mask);
      a0 += __shfl_xor(a0, mask);
      a1 += __shfl_xor(a1, mask);
      a2 += __shfl_xor(a2, mask);
      a3 += __shfl_xor(a3, mask);
      a4 += __shfl_xor(a4, mask);
      a5 += __shfl_xor(a5, mask);
      a6 += __shfl_xor(a6, mask);
      a7 += __shfl_xor(a7, mask);
    }
    if (g == 0 && valid) {
      float inv = (dsum > 0.f) ? 1.0f / dsum : 0.f;
      float4 b0 = ((const float4*)bias)[2 * m];
      float4 b1 = ((const float4*)bias)[2 * m + 1];
      float4 o0 = {a0 * inv + b0.x, a1 * inv + b0.y,
                   a2 * inv + b0.z, a3 * inv + b0.w};
      float4 o1 = {a4 * inv + b1.x, a5 * inv + b1.y,
                   a6 * inv + b1.z, a7 * inv + b1.w};
      ((float4*)(out + (size_t)dst * CH))[2 * m] = o0;
      ((float4*)(out + (size_t)dst * CH))[2 * m + 1] = o1;
    }
  }
}

extern "C" void kernel_launch(void* const* d_in, const int* in_sizes, int n_in,
                              void* d_out, int out_size, void* d_ws, size_t ws_size,
                              hipStream_t stream) {
  const float* X = (const float*)d_in[0];
  const int* ei = (const int*)d_in[1];
  const float* W = (const float*)d_in[2];
  const float* al = (const float*)d_in[3];
  const float* ar = (const float*)d_in[4];
  const float* bias = (const float*)d_in[5];
  float* out = (float*)d_out;

  // workspace layout (~22.6 MB); all segments 16 B-aligned
  unsigned* ebuf = (unsigned*)d_ws;                       // NB*BCAP u32 (8.0 MB)
  __bf16* embb = (__bf16*)(ebuf + (size_t)NB * BCAP);     // N*128 bf16 (12.8 MB)
  __bf16* Whi = embb + (size_t)N_NODES * CH;              // 16K bf16
  __bf16* Wlo = Whi + CH * CH;                            // 16K bf16
  __bf16* Vhi = Wlo + CH * CH;                            // 2K bf16
  __bf16* Vlo = Vhi + 16 * CH;                            // 2K bf16
  float* leftp = (float*)(Vlo + 16 * CH);                 // N*8 f32
  float* rightp = leftp + (size_t)N_NODES * HEADS;        // N*8 f32
  int* bucket_cnt = (int*)(rightp + (size_t)N_NODES * HEADS);  // NB int

  k_splitw<<<16, 256, 0, stream>>>(W, al, ar, Whi, Wlo, Vhi, Vlo, bucket_cnt);
  k_prep<<<PA_BLOCKS + EMB_BLOCKS, PA_T, 0, stream>>>(ei, bucket_cnt, ebuf, X,
                                                      Whi, Wlo, Vhi, Vlo, embb,
                                                      leftp, rightp);
  k_aggr<<<AG_BLOCKS, 256, 0, stream>>>(bucket_cnt, ebuf, embb, leftp, rightp, bias, out);
}